// Round 1
// baseline (747.738 us; speedup 1.0000x reference)
//
#include <hip/hip_runtime.h>

typedef __attribute__((ext_vector_type(4))) float  f32x4;
typedef __attribute__((ext_vector_type(8))) __bf16 bf16x8;
typedef __attribute__((ext_vector_type(4))) __bf16 bf16x4;

// ---------------------------------------------------------------------------
// x fp32 -> bf16 (vectorized 8/thread, grid-stride)
// ---------------------------------------------------------------------------
__global__ __launch_bounds__(256) void xconv_kernel(const float* __restrict__ in,
                                                    __bf16* __restrict__ out, long n) {
  long i0 = ((long)blockIdx.x * 256 + threadIdx.x) * 8;
  long stride = (long)gridDim.x * 256 * 8;
  for (long i = i0; i < n; i += stride) {
    f32x4 a = *(const f32x4*)(in + i);
    f32x4 b = *(const f32x4*)(in + i + 4);
    bf16x8 v;
    v[0] = (__bf16)a[0]; v[1] = (__bf16)a[1]; v[2] = (__bf16)a[2]; v[3] = (__bf16)a[3];
    v[4] = (__bf16)b[0]; v[5] = (__bf16)b[1]; v[6] = (__bf16)b[2]; v[7] = (__bf16)b[3];
    *(bf16x8*)(out + i) = v;
  }
}

// ---------------------------------------------------------------------------
// weights: transpose + convert to bf16 (so GEMM reads both operands as [*,K])
// qkv_w [256,768] -> qT [768,256]; proj_w [256,256] -> pT [256,256]
// ---------------------------------------------------------------------------
__global__ __launch_bounds__(256) void wconv_kernel(const float* __restrict__ qw,
                                                    const float* __restrict__ pw,
                                                    __bf16* __restrict__ qT,
                                                    __bf16* __restrict__ pT) {
  int i = blockIdx.x * 256 + threadIdx.x;      // 1024 blocks -> 262144
  if (i < 768 * 256) {
    int n = i >> 8, k = i & 255;
    qT[i] = (__bf16)qw[k * 768 + n];
  } else {
    int j = i - 768 * 256;                     // < 65536
    int n = j >> 8, k = j & 255;
    pT[j] = (__bf16)pw[k * 256 + n];
  }
}

// ---------------------------------------------------------------------------
// Swin-v2 continuous relative position bias table -> [8][64][64] f32
// ---------------------------------------------------------------------------
__global__ __launch_bounds__(256) void cpb_kernel(const float* __restrict__ w1,
                                                  const float* __restrict__ b1,
                                                  const float* __restrict__ w2,
                                                  float* __restrict__ bias) {
  int pair = blockIdx.x * 256 + threadIdx.x;   // 4096 pairs (l, m)
  int lq = pair >> 6, mk = pair & 63;
  float d0 = (float)((lq >> 3) - (mk >> 3));
  float d1 = (float)((lq & 7) - (mk & 7));
  float v0 = d0 * (8.0f / 7.0f);
  float v1 = d1 * (8.0f / 7.0f);
  float s0 = (v0 > 0.f) ? 1.f : ((v0 < 0.f) ? -1.f : 0.f);
  float s1 = (v1 > 0.f) ? 1.f : ((v1 < 0.f) ? -1.f : 0.f);
  float r0 = s0 * log2f(fabsf(v0) + 1.0f) * (1.0f / 3.0f);   // /log2(8)
  float r1 = s1 * log2f(fabsf(v1) + 1.0f) * (1.0f / 3.0f);
  float acc[8] = {0.f, 0.f, 0.f, 0.f, 0.f, 0.f, 0.f, 0.f};
  #pragma unroll 4
  for (int j = 0; j < 512; ++j) {
    float h = fmaxf(r0 * w1[j] + r1 * w1[512 + j] + b1[j], 0.0f);
    #pragma unroll
    for (int q = 0; q < 8; ++q) acc[q] += h * w2[j * 8 + q];
  }
  #pragma unroll
  for (int q = 0; q < 8; ++q) {
    float s = 16.0f / (1.0f + __expf(-acc[q]));
    bias[(q * 64 + lq) * 64 + mk] = s;
  }
}

// ---------------------------------------------------------------------------
// GEMM: C[M,N] = A[M,256] @ BT[N,256]^T  (bf16 in, fp32 accum)
// 128x128 tile, 256 threads (4 waves, 2x2), mfma_f32_16x16x32_bf16.
// EPI 0: bf16 out + qkv bias concat(q_bias, 0, v_bias). EPI 1: f32 out + proj_b.
// LDS XOR-swizzled (chunk ^= row&7) to keep ds_read_b128 2-way max.
// ---------------------------------------------------------------------------
template <int EPI>
__global__ __launch_bounds__(256) void gemm_bt_kernel(
    const __bf16* __restrict__ A, const __bf16* __restrict__ BT,
    void* __restrict__ Cout, int N,
    const float* __restrict__ bq, const float* __restrict__ bv,
    const float* __restrict__ pb)
{
  const int K = 256;
  __shared__ __align__(16) __bf16 lA[128 * 64];
  __shared__ __align__(16) __bf16 lB[128 * 64];
  int t = threadIdx.x;
  int wv = t >> 6, l = t & 63;
  int g = l >> 4, c = l & 15;
  int wr = wv >> 1, wc = wv & 1;
  int mblk = blockIdx.y, nblk = blockIdx.x;

  int srow = wv * 8 + (l >> 3);          // staging row (within 32-row pass)
  const __bf16* Ab = A + (size_t)mblk * 128 * K;
  const __bf16* Bb = BT + (size_t)nblk * 128 * K;

  f32x4 acc[4][4];
  #pragma unroll
  for (int i = 0; i < 4; ++i)
    #pragma unroll
    for (int j = 0; j < 4; ++j) acc[i][j] = (f32x4){0.f, 0.f, 0.f, 0.f};

  for (int kt = 0; kt < 4; ++kt) {
    bf16x8 ra[4], rb[4];
    #pragma unroll
    for (int p = 0; p < 4; ++p) {
      ra[p] = *(const bf16x8*)(Ab + (size_t)(p * 32 + srow) * K + kt * 64 + (l & 7) * 8);
      rb[p] = *(const bf16x8*)(Bb + (size_t)(p * 32 + srow) * K + kt * 64 + (l & 7) * 8);
    }
    __syncthreads();
    #pragma unroll
    for (int p = 0; p < 4; ++p) {
      int row = p * 32 + srow;
      int phys = (l & 7) ^ (row & 7);
      *(bf16x8*)&lA[row * 64 + phys * 8] = ra[p];
      *(bf16x8*)&lB[row * 64 + phys * 8] = rb[p];
    }
    __syncthreads();
    #pragma unroll
    for (int kk = 0; kk < 2; ++kk) {
      bf16x8 af[4], bfr[4];
      #pragma unroll
      for (int mt = 0; mt < 4; ++mt) {
        int row = wr * 64 + mt * 16 + c;
        int ch = ((kk << 2) | g) ^ (c & 7);
        af[mt] = *(const bf16x8*)&lA[row * 64 + ch * 8];
      }
      #pragma unroll
      for (int nt = 0; nt < 4; ++nt) {
        int row = wc * 64 + nt * 16 + c;
        int ch = ((kk << 2) | g) ^ (c & 7);
        bfr[nt] = *(const bf16x8*)&lB[row * 64 + ch * 8];
      }
      #pragma unroll
      for (int mt = 0; mt < 4; ++mt)
        #pragma unroll
        for (int nt = 0; nt < 4; ++nt)
          acc[mt][nt] = __builtin_amdgcn_mfma_f32_16x16x32_bf16(af[mt], bfr[nt], acc[mt][nt], 0, 0, 0);
    }
  }

  #pragma unroll
  for (int mt = 0; mt < 4; ++mt) {
    #pragma unroll
    for (int nt = 0; nt < 4; ++nt) {
      int row0 = mblk * 128 + wr * 64 + mt * 16 + 4 * g;
      int col  = nblk * 128 + wc * 64 + nt * 16 + c;
      if (EPI == 0) {
        float bias = (col < 256) ? bq[col] : ((col < 512) ? 0.0f : bv[col - 512]);
        __bf16* o = (__bf16*)Cout;
        #pragma unroll
        for (int i = 0; i < 4; ++i)
          o[(size_t)(row0 + i) * N + col] = (__bf16)(acc[mt][nt][i] + bias);
      } else {
        float bias = pb[col];
        float* o = (float*)Cout;
        #pragma unroll
        for (int i = 0; i < 4; ++i)
          o[(size_t)(row0 + i) * N + col] = acc[mt][nt][i] + bias;
      }
    }
  }
}

// ---------------------------------------------------------------------------
// Windowed cosine attention. One block = (batch, window); 4 waves; each wave
// does heads wv and wv+4. Cyclic shift folded into token index map.
// T = Kn @ Qn'^T via mfma(K,Q); softmax over k (in-lane 16 + shfl 16/32);
// P^T -> LDS; O^T = V^T @ P^T; divide by row sums at the end.
// ---------------------------------------------------------------------------
__device__ __forceinline__ int win_region(int tok, int wi, int wj) {
  int r = tok >> 3, cc = tok & 7;
  int rh = (wi == 15) ? ((r < 4) ? 1 : 2) : 0;
  int rw = (wj == 15) ? ((cc < 4) ? 1 : 2) : 0;
  return rh * 3 + rw;
}

__global__ __launch_bounds__(256) void attn_kernel(
    const __bf16* __restrict__ qkv, const float* __restrict__ scale,
    const float* __restrict__ bias, __bf16* __restrict__ out)
{
  __shared__ __align__(16) __bf16 lP[4][64 * 72];   // P^T per wave, [q][k] pad 72
  __shared__ __align__(16) __bf16 lV[4][64 * 48];   // V per wave, [tok][unit] pad 48
  int t = threadIdx.x;
  int wv = t >> 6, l = t & 63;
  int g = l >> 4, c = l & 15;
  int win = blockIdx.x, b = blockIdx.y;
  int wi = win >> 4, wj = win & 15;
  __bf16* Pw = &lP[wv][0];
  __bf16* Vw = &lV[wv][0];
  const f32x4 zz = {0.f, 0.f, 0.f, 0.f};

  long tokq[4], toko[4];
  #pragma unroll
  for (int i = 0; i < 4; ++i) {
    int tok = 16 * i + c;
    int ht = (wi * 8 + (tok >> 3) + 4) & 127;
    int wt = (wj * 8 + (tok & 7) + 4) & 127;
    long base = ((long)(b * 128 + ht)) * 128 + wt;
    tokq[i] = base * 768;
    toko[i] = base * 256;
  }

  for (int hx = 0; hx < 2; ++hx) {
    int h = wv + hx * 4;
    float ls = __expf(fminf(scale[h], 4.6051701859880914f));  // ln(100)

    bf16x8 kf[4], qf[4];
    #pragma unroll
    for (int i = 0; i < 4; ++i) {
      // K fragment (A operand): token 16i+c, units g*8..g*8+7 ; l2-normalize
      bf16x8 kv = *(const bf16x8*)(qkv + tokq[i] + h * 96 + 32 + g * 8);
      float f[8], ss = 0.f;
      #pragma unroll
      for (int j = 0; j < 8; ++j) { f[j] = (float)kv[j]; ss += f[j] * f[j]; }
      ss += __shfl_xor(ss, 16); ss += __shfl_xor(ss, 32);
      float rn = rsqrtf(fmaxf(ss, 1.55e-5f));
      #pragma unroll
      for (int j = 0; j < 8; ++j) kf[i][j] = (__bf16)(f[j] * rn);
      // Q fragment (B operand): normalize * logit_scale
      bf16x8 qv = *(const bf16x8*)(qkv + tokq[i] + h * 96 + g * 8);
      ss = 0.f;
      #pragma unroll
      for (int j = 0; j < 8; ++j) { f[j] = (float)qv[j]; ss += f[j] * f[j]; }
      ss += __shfl_xor(ss, 16); ss += __shfl_xor(ss, 32);
      rn = rsqrtf(fmaxf(ss, 1.55e-5f)) * ls;
      #pragma unroll
      for (int j = 0; j < 8; ++j) qf[i][j] = (__bf16)(f[j] * rn);
      // V -> LDS [tok][unit]
      *(bf16x8*)&Vw[(16 * i + c) * 48 + g * 8] =
          *(const bf16x8*)(qkv + tokq[i] + h * 96 + 64 + g * 8);
    }

    float rsum[4];
    #pragma unroll
    for (int nt = 0; nt < 4; ++nt) {
      f32x4 tt[4];
      #pragma unroll
      for (int mt = 0; mt < 4; ++mt)
        tt[mt] = __builtin_amdgcn_mfma_f32_16x16x32_bf16(kf[mt], qf[nt], zz, 0, 0, 0);
      int q = nt * 16 + c;               // this lane's q-token (column of T)
      int regq = win_region(q, wi, wj);
      float p[16], mx = -1e30f;
      #pragma unroll
      for (int mt = 0; mt < 4; ++mt) {
        f32x4 bb = *(const f32x4*)&bias[(h * 64 + q) * 64 + mt * 16 + 4 * g];
        #pragma unroll
        for (int i = 0; i < 4; ++i) {
          int k = mt * 16 + 4 * g + i;
          float v = tt[mt][i] + bb[i];
          if (win_region(k, wi, wj) != regq) v -= 100.0f;
          p[mt * 4 + i] = v;
          mx = fmaxf(mx, v);
        }
      }
      mx = fmaxf(mx, __shfl_xor(mx, 16));
      mx = fmaxf(mx, __shfl_xor(mx, 32));
      float sum = 0.f;
      #pragma unroll
      for (int j = 0; j < 16; ++j) { p[j] = __expf(p[j] - mx); sum += p[j]; }
      sum += __shfl_xor(sum, 16); sum += __shfl_xor(sum, 32);
      rsum[nt] = sum;
      #pragma unroll
      for (int mt = 0; mt < 4; ++mt) {
        bf16x4 px = { (__bf16)p[mt * 4 + 0], (__bf16)p[mt * 4 + 1],
                      (__bf16)p[mt * 4 + 2], (__bf16)p[mt * 4 + 3] };
        *(bf16x4*)&Pw[q * 72 + mt * 16 + 4 * g] = px;   // LDS_P[q][k0..k0+3]
      }
    }

    // O^T = V^T @ P^T   (M=32 units as 2 tiles, N=64 q, K=64 tokens)
    #pragma unroll
    for (int mh = 0; mh < 2; ++mh) {
      f32x4 oacc[4];
      #pragma unroll
      for (int nt = 0; nt < 4; ++nt) oacc[nt] = zz;
      #pragma unroll
      for (int ks = 0; ks < 2; ++ks) {
        bf16x8 va;
        #pragma unroll
        for (int j = 0; j < 8; ++j)
          va[j] = Vw[(32 * ks + 8 * g + j) * 48 + 16 * mh + c];   // V^T[unit][ktok]
        #pragma unroll
        for (int nt = 0; nt < 4; ++nt) {
          bf16x8 pfr = *(const bf16x8*)&Pw[(nt * 16 + c) * 72 + 32 * ks + 8 * g];
          oacc[nt] = __builtin_amdgcn_mfma_f32_16x16x32_bf16(va, pfr, oacc[nt], 0, 0, 0);
        }
      }
      #pragma unroll
      for (int nt = 0; nt < 4; ++nt) {
        float rinv = 1.0f / rsum[nt];
        bf16x4 ov = { (__bf16)(oacc[nt][0] * rinv), (__bf16)(oacc[nt][1] * rinv),
                      (__bf16)(oacc[nt][2] * rinv), (__bf16)(oacc[nt][3] * rinv) };
        *(bf16x4*)(out + toko[nt] + h * 32 + 16 * mh + 4 * g) = ov;
      }
    }
  }
}

// ---------------------------------------------------------------------------
extern "C" void kernel_launch(void* const* d_in, const int* in_sizes, int n_in,
                              void* d_out, int out_size, void* d_ws, size_t ws_size,
                              hipStream_t stream)
{
  const float* x      = (const float*)d_in[0];
  const float* qkv_w  = (const float*)d_in[1];
  const float* q_bias = (const float*)d_in[2];
  const float* v_bias = (const float*)d_in[3];
  const float* scale  = (const float*)d_in[4];
  const float* cpb_w1 = (const float*)d_in[5];
  const float* cpb_b1 = (const float*)d_in[6];
  const float* cpb_w2 = (const float*)d_in[7];
  const float* proj_w = (const float*)d_in[8];
  const float* proj_b = (const float*)d_in[9];

  char* ws = (char*)d_ws;
  // layout (bytes):
  //   [0, 402653184)               qkv bf16  [262144][768]
  //   [402653184, 536870912)       x16 bf16  [262144][256]   (aliased: attn out)
  //   [536870912, 537264128)       qkv_w^T bf16 [768][256]
  //   [537264128, 537395200)       proj_w^T bf16 [256][256]
  //   [537395200, 537526272)       rel-bias f32 [8][64][64]
  __bf16* qkv  = (__bf16*)(ws);
  __bf16* x16  = (__bf16*)(ws + 402653184LL);
  __bf16* wqT  = (__bf16*)(ws + 536870912LL);
  __bf16* wpT  = (__bf16*)(ws + 537264128LL);
  float*  bias = (float*) (ws + 537395200LL);
  __bf16* aout = x16;   // reuse x16 region after qkv GEMM consumed it

  xconv_kernel<<<2048, 256, 0, stream>>>(x, x16, (long)262144 * 256);
  wconv_kernel<<<1024, 256, 0, stream>>>(qkv_w, proj_w, wqT, wpT);
  cpb_kernel<<<16, 256, 0, stream>>>(cpb_w1, cpb_b1, cpb_w2, bias);
  gemm_bt_kernel<0><<<dim3(6, 2048), 256, 0, stream>>>(x16, wqT, qkv, 768,
                                                       q_bias, v_bias, nullptr);
  attn_kernel<<<dim3(256, 16), 256, 0, stream>>>(qkv, scale, bias, aout);
  gemm_bt_kernel<1><<<dim3(2, 2048), 256, 0, stream>>>(aout, wpT, d_out, 256,
                                                       nullptr, nullptr, proj_b);
}

// Round 2
// 747.073 us; speedup vs baseline: 1.0009x; 1.0009x over previous
//
#include <hip/hip_runtime.h>

typedef __attribute__((ext_vector_type(4))) float          f32x4;
typedef __attribute__((ext_vector_type(8))) __bf16         bf16x8;
typedef __attribute__((ext_vector_type(4))) __bf16         bf16x4;
typedef __attribute__((ext_vector_type(8))) unsigned short u16x8;

// ---------------------------------------------------------------------------
// weights: transpose + convert to bf16 (so GEMM reads both operands as [*,K])
// qkv_w [256,768] -> qT [768,256]; proj_w [256,256] -> pT [256,256]
// ---------------------------------------------------------------------------
__global__ __launch_bounds__(256) void wconv_kernel(const float* __restrict__ qw,
                                                    const float* __restrict__ pw,
                                                    __bf16* __restrict__ qT,
                                                    __bf16* __restrict__ pT) {
  int i = blockIdx.x * 256 + threadIdx.x;      // 1024 blocks -> 262144
  if (i < 768 * 256) {
    int n = i >> 8, k = i & 255;
    qT[i] = (__bf16)qw[k * 768 + n];
  } else {
    int j = i - 768 * 256;                     // < 65536
    int n = j >> 8, k = j & 255;
    pT[j] = (__bf16)pw[k * 256 + n];
  }
}

// ---------------------------------------------------------------------------
// Swin-v2 continuous relative position bias table -> [8][64][64] f32
// ---------------------------------------------------------------------------
__global__ __launch_bounds__(256) void cpb_kernel(const float* __restrict__ w1,
                                                  const float* __restrict__ b1,
                                                  const float* __restrict__ w2,
                                                  float* __restrict__ bias) {
  int pair = blockIdx.x * 256 + threadIdx.x;   // 4096 pairs (l, m)
  int lq = pair >> 6, mk = pair & 63;
  float d0 = (float)((lq >> 3) - (mk >> 3));
  float d1 = (float)((lq & 7) - (mk & 7));
  float v0 = d0 * (8.0f / 7.0f);
  float v1 = d1 * (8.0f / 7.0f);
  float s0 = (v0 > 0.f) ? 1.f : ((v0 < 0.f) ? -1.f : 0.f);
  float s1 = (v1 > 0.f) ? 1.f : ((v1 < 0.f) ? -1.f : 0.f);
  float r0 = s0 * log2f(fabsf(v0) + 1.0f) * (1.0f / 3.0f);   // /log2(8)
  float r1 = s1 * log2f(fabsf(v1) + 1.0f) * (1.0f / 3.0f);
  float acc[8] = {0.f, 0.f, 0.f, 0.f, 0.f, 0.f, 0.f, 0.f};
  #pragma unroll 4
  for (int j = 0; j < 512; ++j) {
    float h = fmaxf(r0 * w1[j] + r1 * w1[512 + j] + b1[j], 0.0f);
    #pragma unroll
    for (int q = 0; q < 8; ++q) acc[q] += h * w2[j * 8 + q];
  }
  #pragma unroll
  for (int q = 0; q < 8; ++q) {
    float s = 16.0f / (1.0f + __expf(-acc[q]));
    bias[(q * 64 + lq) * 64 + mk] = s;
  }
}

// ---------------------------------------------------------------------------
// GEMM: C[M,N] = A[M,256] @ BT[N,256]^T  (fp32-accum, bf16 MFMA)
// 128x128 tile, 256 threads (4 waves, 2x2), mfma_f32_16x16x32_bf16.
// EPI 0: A fp32 (converted during staging), bf16 out + qkv bias.
// EPI 1: A bf16, f32 out + proj_b.
// 1-D grid with bijective XCD swizzle (nwg % 8 == 0).
// LDS XOR-swizzled (chunk ^= row&7) to keep ds_read_b128 conflict-light.
// ---------------------------------------------------------------------------
template <int EPI>
__global__ __launch_bounds__(256) void gemm_bt_kernel(
    const void* __restrict__ Ain, const __bf16* __restrict__ BT,
    void* __restrict__ Cout, int N, int NB,
    const float* __restrict__ bq, const float* __restrict__ bv,
    const float* __restrict__ pb)
{
  const int K = 256;
  __shared__ __align__(16) __bf16 lA[128 * 64];
  __shared__ __align__(16) __bf16 lB[128 * 64];
  int t = threadIdx.x;
  int wv = t >> 6, l = t & 63;
  int g = l >> 4, c = l & 15;
  int wr = wv >> 1, wc = wv & 1;

  // XCD swizzle: consecutive lin (same A-panel) stay on one XCD
  int cpx = gridDim.x >> 3;
  int lin = (blockIdx.x & 7) * cpx + (blockIdx.x >> 3);
  int mblk = lin / NB;
  int nblk = lin - mblk * NB;

  int srow = wv * 8 + (l >> 3);          // staging row (within 32-row pass)
  const __bf16* Bb = BT + (size_t)nblk * 128 * K;

  f32x4 acc[4][4];
  #pragma unroll
  for (int i = 0; i < 4; ++i)
    #pragma unroll
    for (int j = 0; j < 4; ++j) acc[i][j] = (f32x4){0.f, 0.f, 0.f, 0.f};

  for (int kt = 0; kt < 4; ++kt) {
    bf16x8 ra[4], rb[4];
    #pragma unroll
    for (int p = 0; p < 4; ++p) {
      if (EPI == 0) {
        const float* Af = (const float*)Ain + (size_t)mblk * 128 * K;
        const float* src = Af + (size_t)(p * 32 + srow) * K + kt * 64 + (l & 7) * 8;
        f32x4 a0 = *(const f32x4*)src;
        f32x4 a1 = *(const f32x4*)(src + 4);
        #pragma unroll
        for (int j = 0; j < 4; ++j) { ra[p][j] = (__bf16)a0[j]; ra[p][4 + j] = (__bf16)a1[j]; }
      } else {
        const __bf16* Ab = (const __bf16*)Ain + (size_t)mblk * 128 * K;
        ra[p] = *(const bf16x8*)(Ab + (size_t)(p * 32 + srow) * K + kt * 64 + (l & 7) * 8);
      }
      rb[p] = *(const bf16x8*)(Bb + (size_t)(p * 32 + srow) * K + kt * 64 + (l & 7) * 8);
    }
    __syncthreads();
    #pragma unroll
    for (int p = 0; p < 4; ++p) {
      int row = p * 32 + srow;
      int phys = (l & 7) ^ (row & 7);
      *(bf16x8*)&lA[row * 64 + phys * 8] = ra[p];
      *(bf16x8*)&lB[row * 64 + phys * 8] = rb[p];
    }
    __syncthreads();
    #pragma unroll
    for (int kk = 0; kk < 2; ++kk) {
      bf16x8 af[4], bfr[4];
      #pragma unroll
      for (int mt = 0; mt < 4; ++mt) {
        int row = wr * 64 + mt * 16 + c;
        int ch = ((kk << 2) | g) ^ (c & 7);
        af[mt] = *(const bf16x8*)&lA[row * 64 + ch * 8];
      }
      #pragma unroll
      for (int nt = 0; nt < 4; ++nt) {
        int row = wc * 64 + nt * 16 + c;
        int ch = ((kk << 2) | g) ^ (c & 7);
        bfr[nt] = *(const bf16x8*)&lB[row * 64 + ch * 8];
      }
      #pragma unroll
      for (int mt = 0; mt < 4; ++mt)
        #pragma unroll
        for (int nt = 0; nt < 4; ++nt)
          acc[mt][nt] = __builtin_amdgcn_mfma_f32_16x16x32_bf16(af[mt], bfr[nt], acc[mt][nt], 0, 0, 0);
    }
  }

  #pragma unroll
  for (int mt = 0; mt < 4; ++mt) {
    #pragma unroll
    for (int nt = 0; nt < 4; ++nt) {
      int row0 = mblk * 128 + wr * 64 + mt * 16 + 4 * g;
      int col  = nblk * 128 + wc * 64 + nt * 16 + c;
      if (EPI == 0) {
        float bias = (col < 256) ? bq[col] : ((col < 512) ? 0.0f : bv[col - 512]);
        __bf16* o = (__bf16*)Cout;
        #pragma unroll
        for (int i = 0; i < 4; ++i)
          o[(size_t)(row0 + i) * N + col] = (__bf16)(acc[mt][nt][i] + bias);
      } else {
        float bias = pb[col];
        float* o = (float*)Cout;
        #pragma unroll
        for (int i = 0; i < 4; ++i)
          o[(size_t)(row0 + i) * N + col] = acc[mt][nt][i] + bias;
      }
    }
  }
}

// ---------------------------------------------------------------------------
// Windowed cosine attention. One block = (batch, window); 4 waves; each wave
// does heads wv and wv+4. Cyclic shift folded into token index map.
// T = Kn @ Qn'^T via mfma(K,Q); softmax over k (in-lane 16 + shfl 16/32);
// P^T -> LDS (only LDS use, 36.9 KB -> 4 blocks/CU); V^T fragment loaded
// directly from global as 32 u16/head (L2-resident).
// ---------------------------------------------------------------------------
__device__ __forceinline__ int win_region(int tok, int wi, int wj) {
  int r = tok >> 3, cc = tok & 7;
  int rh = (wi == 15) ? ((r < 4) ? 1 : 2) : 0;
  int rw = (wj == 15) ? ((cc < 4) ? 1 : 2) : 0;
  return rh * 3 + rw;
}

__global__ __launch_bounds__(256, 4) void attn_kernel(
    const __bf16* __restrict__ qkv, const float* __restrict__ scale,
    const float* __restrict__ bias, __bf16* __restrict__ out)
{
  __shared__ __align__(16) __bf16 lP[4][64 * 72];   // P^T per wave, [q][k] pad 72
  int t = threadIdx.x;
  int wv = t >> 6, l = t & 63;
  int g = l >> 4, c = l & 15;
  int win = blockIdx.x, b = blockIdx.y;
  int wi = win >> 4, wj = win & 15;
  bool edge = (wi == 15) || (wj == 15);
  __bf16* Pw = &lP[wv][0];
  const f32x4 zz = {0.f, 0.f, 0.f, 0.f};

  // element offsets (fit int32: max 262144*768 < 2^31)
  int tokq[4], toko[4];
  #pragma unroll
  for (int i = 0; i < 4; ++i) {
    int tok = 16 * i + c;
    int ht = (wi * 8 + (tok >> 3) + 4) & 127;
    int wt = (wj * 8 + (tok & 7) + 4) & 127;
    int base = (b * 128 + ht) * 128 + wt;
    tokq[i] = base * 768;
    toko[i] = base * 256;
  }
  // V^T fragment addresses: tok = 32*ks + 8*g + j  (rows uniform per group)
  int vadr[2][8];
  #pragma unroll
  for (int ks = 0; ks < 2; ++ks) {
    int ht = (wi * 8 + 4 * ks + g + 4) & 127;
    #pragma unroll
    for (int j = 0; j < 8; ++j) {
      int wt = (wj * 8 + j + 4) & 127;
      vadr[ks][j] = ((b * 128 + ht) * 128 + wt) * 768 + c;
    }
  }
  const unsigned short* qu = (const unsigned short*)qkv;

  for (int hx = 0; hx < 2; ++hx) {
    int h = wv + hx * 4;
    float ls = __expf(fminf(scale[h], 4.6051701859880914f));  // ln(100)

    // issue V^T loads early (32 u16) — hidden under normalize + QK
    u16x8 rv[2][2];   // [mh][ks]
    #pragma unroll
    for (int ks = 0; ks < 2; ++ks)
      #pragma unroll
      for (int j = 0; j < 8; ++j) {
        int a = vadr[ks][j] + h * 96 + 64;
        rv[0][ks][j] = qu[a];
        rv[1][ks][j] = qu[a + 16];
      }

    bf16x8 kf[4], qf[4];
    #pragma unroll
    for (int i = 0; i < 4; ++i) {
      // K fragment (A operand): token 16i+c, units g*8..g*8+7 ; l2-normalize
      bf16x8 kv = *(const bf16x8*)(qkv + tokq[i] + h * 96 + 32 + g * 8);
      float f[8], ss = 0.f;
      #pragma unroll
      for (int j = 0; j < 8; ++j) { f[j] = (float)kv[j]; ss += f[j] * f[j]; }
      ss += __shfl_xor(ss, 16); ss += __shfl_xor(ss, 32);
      float rn = rsqrtf(fmaxf(ss, 1.55e-5f));
      #pragma unroll
      for (int j = 0; j < 8; ++j) kf[i][j] = (__bf16)(f[j] * rn);
      // Q fragment (B operand): normalize * logit_scale
      bf16x8 qv = *(const bf16x8*)(qkv + tokq[i] + h * 96 + g * 8);
      ss = 0.f;
      #pragma unroll
      for (int j = 0; j < 8; ++j) { f[j] = (float)qv[j]; ss += f[j] * f[j]; }
      ss += __shfl_xor(ss, 16); ss += __shfl_xor(ss, 32);
      rn = rsqrtf(fmaxf(ss, 1.55e-5f)) * ls;
      #pragma unroll
      for (int j = 0; j < 8; ++j) qf[i][j] = (__bf16)(f[j] * rn);
    }

    float rsum[4];
    #pragma unroll
    for (int nt = 0; nt < 4; ++nt) {
      f32x4 tt[4];
      #pragma unroll
      for (int mt = 0; mt < 4; ++mt)
        tt[mt] = __builtin_amdgcn_mfma_f32_16x16x32_bf16(kf[mt], qf[nt], zz, 0, 0, 0);
      int q = nt * 16 + c;               // this lane's q-token (column of T)
      float p[16];
      #pragma unroll
      for (int mt = 0; mt < 4; ++mt) {
        f32x4 bb = *(const f32x4*)&bias[(h * 64 + q) * 64 + mt * 16 + 4 * g];
        #pragma unroll
        for (int i = 0; i < 4; ++i) p[mt * 4 + i] = tt[mt][i] + bb[i];
      }
      if (edge) {
        int regq = win_region(q, wi, wj);
        #pragma unroll
        for (int mt = 0; mt < 4; ++mt)
          #pragma unroll
          for (int i = 0; i < 4; ++i) {
            int k = mt * 16 + 4 * g + i;
            if (win_region(k, wi, wj) != regq) p[mt * 4 + i] -= 100.0f;
          }
      }
      float mx = -1e30f;
      #pragma unroll
      for (int j = 0; j < 16; ++j) mx = fmaxf(mx, p[j]);
      mx = fmaxf(mx, __shfl_xor(mx, 16));
      mx = fmaxf(mx, __shfl_xor(mx, 32));
      float sum = 0.f;
      #pragma unroll
      for (int j = 0; j < 16; ++j) { p[j] = __expf(p[j] - mx); sum += p[j]; }
      sum += __shfl_xor(sum, 16); sum += __shfl_xor(sum, 32);
      rsum[nt] = sum;
      #pragma unroll
      for (int mt = 0; mt < 4; ++mt) {
        bf16x4 px = { (__bf16)p[mt * 4 + 0], (__bf16)p[mt * 4 + 1],
                      (__bf16)p[mt * 4 + 2], (__bf16)p[mt * 4 + 3] };
        *(bf16x4*)&Pw[q * 72 + mt * 16 + 4 * g] = px;   // LDS_P[q][k0..k0+3]
      }
    }

    // O^T = V^T @ P^T   (M=32 units as 2 tiles, N=64 q, K=64 tokens)
    #pragma unroll
    for (int mh = 0; mh < 2; ++mh) {
      f32x4 oacc[4];
      #pragma unroll
      for (int nt = 0; nt < 4; ++nt) oacc[nt] = zz;
      #pragma unroll
      for (int ks = 0; ks < 2; ++ks) {
        bf16x8 va = __builtin_bit_cast(bf16x8, rv[mh][ks]);
        #pragma unroll
        for (int nt = 0; nt < 4; ++nt) {
          bf16x8 pfr = *(const bf16x8*)&Pw[(nt * 16 + c) * 72 + 32 * ks + 8 * g];
          oacc[nt] = __builtin_amdgcn_mfma_f32_16x16x32_bf16(va, pfr, oacc[nt], 0, 0, 0);
        }
      }
      #pragma unroll
      for (int nt = 0; nt < 4; ++nt) {
        float rinv = 1.0f / rsum[nt];
        bf16x4 ov = { (__bf16)(oacc[nt][0] * rinv), (__bf16)(oacc[nt][1] * rinv),
                      (__bf16)(oacc[nt][2] * rinv), (__bf16)(oacc[nt][3] * rinv) };
        *(bf16x4*)(out + toko[nt] + h * 32 + 16 * mh + 4 * g) = ov;
      }
    }
  }
}

// ---------------------------------------------------------------------------
extern "C" void kernel_launch(void* const* d_in, const int* in_sizes, int n_in,
                              void* d_out, int out_size, void* d_ws, size_t ws_size,
                              hipStream_t stream)
{
  const float* x      = (const float*)d_in[0];
  const float* qkv_w  = (const float*)d_in[1];
  const float* q_bias = (const float*)d_in[2];
  const float* v_bias = (const float*)d_in[3];
  const float* scale  = (const float*)d_in[4];
  const float* cpb_w1 = (const float*)d_in[5];
  const float* cpb_b1 = (const float*)d_in[6];
  const float* cpb_w2 = (const float*)d_in[7];
  const float* proj_w = (const float*)d_in[8];
  const float* proj_b = (const float*)d_in[9];

  char* ws = (char*)d_ws;
  // layout (bytes):
  //   [0, 402653184)               qkv bf16  [262144][768]
  //   [402653184, 536870912)       attn-out bf16 [262144][256]
  //   [536870912, 537264128)       qkv_w^T bf16 [768][256]
  //   [537264128, 537395200)       proj_w^T bf16 [256][256]
  //   [537395200, 537526272)       rel-bias f32 [8][64][64]
  __bf16* qkv  = (__bf16*)(ws);
  __bf16* aout = (__bf16*)(ws + 402653184LL);
  __bf16* wqT  = (__bf16*)(ws + 536870912LL);
  __bf16* wpT  = (__bf16*)(ws + 537264128LL);
  float*  bias = (float*) (ws + 537395200LL);

  wconv_kernel<<<1024, 256, 0, stream>>>(qkv_w, proj_w, wqT, wpT);
  cpb_kernel<<<16, 256, 0, stream>>>(cpb_w1, cpb_b1, cpb_w2, bias);
  gemm_bt_kernel<0><<<12288, 256, 0, stream>>>(x, wqT, qkv, 768, 6,
                                               q_bias, v_bias, nullptr);
  attn_kernel<<<dim3(256, 16), 256, 0, stream>>>(qkv, scale, bias, aout);
  gemm_bt_kernel<1><<<4096, 256, 0, stream>>>(aout, wpT, d_out, 256, 2,
                                              nullptr, nullptr, proj_b);
}

// Round 4
// 407.045 us; speedup vs baseline: 1.8370x; 1.8354x over previous
//
#include <hip/hip_runtime.h>

typedef __attribute__((ext_vector_type(4))) float  f32x4;
typedef __attribute__((ext_vector_type(8))) __bf16 bf16x8;
typedef __attribute__((ext_vector_type(4))) __bf16 bf16x4;

// ---------------------------------------------------------------------------
// weight prep:
//  - W2: qkv weights packed in MFMA A-fragment order per (head, feat-tile, kstep):
//        W2[((h*6+ft)*8+ks)*64 + l][j] = qw[(ks*32+(l>>4)*8+j)*768 + (h*96+ft*16+(l&15))]
//  - pT: proj_w transposed to [N=256][K=256] bf16
//  - bcat: concat(q_bias, 0, v_bias) fp32[768]
// ---------------------------------------------------------------------------
__global__ __launch_bounds__(256) void wprep_kernel(const float* __restrict__ qw,
                                                    const float* __restrict__ pw,
                                                    const float* __restrict__ qb,
                                                    const float* __restrict__ vb,
                                                    __bf16* __restrict__ W2,
                                                    __bf16* __restrict__ pT,
                                                    float* __restrict__ bcat) {
  int i = blockIdx.x * 256 + threadIdx.x;
  if (i < 24576) {                       // 8 heads * 6 ft * 8 ks * 64 lanes
    int h = i / 3072, rem = i - h * 3072;
    int ft = rem >> 9, rem2 = rem & 511;
    int ks = rem2 >> 6, l = rem2 & 63;
    int g = l >> 4, c = l & 15;
    int col = h * 96 + ft * 16 + c;
    bf16x8 v;
    #pragma unroll
    for (int j = 0; j < 8; ++j)
      v[j] = (__bf16)qw[(ks * 32 + g * 8 + j) * 768 + col];
    *(bf16x8*)(W2 + (size_t)i * 8) = v;
  } else if (i < 24576 + 65536) {
    int j = i - 24576;
    int n = j >> 8, k = j & 255;
    pT[j] = (__bf16)pw[k * 256 + n];
  } else if (i < 24576 + 65536 + 768) {
    int cdx = i - 24576 - 65536;
    bcat[cdx] = (cdx < 256) ? qb[cdx] : ((cdx < 512) ? 0.0f : vb[cdx - 512]);
  }
}

// ---------------------------------------------------------------------------
// Swin-v2 continuous relative position bias table -> [8][64][64] f32
// ---------------------------------------------------------------------------
__global__ __launch_bounds__(256) void cpb_kernel(const float* __restrict__ w1,
                                                  const float* __restrict__ b1,
                                                  const float* __restrict__ w2,
                                                  float* __restrict__ bias) {
  int pair = blockIdx.x * 256 + threadIdx.x;   // 4096 pairs (l, m)
  int lq = pair >> 6, mk = pair & 63;
  float d0 = (float)((lq >> 3) - (mk >> 3));
  float d1 = (float)((lq & 7) - (mk & 7));
  float v0 = d0 * (8.0f / 7.0f);
  float v1 = d1 * (8.0f / 7.0f);
  float s0 = (v0 > 0.f) ? 1.f : ((v0 < 0.f) ? -1.f : 0.f);
  float s1 = (v1 > 0.f) ? 1.f : ((v1 < 0.f) ? -1.f : 0.f);
  float r0 = s0 * log2f(fabsf(v0) + 1.0f) * (1.0f / 3.0f);
  float r1 = s1 * log2f(fabsf(v1) + 1.0f) * (1.0f / 3.0f);
  float acc[8] = {0.f, 0.f, 0.f, 0.f, 0.f, 0.f, 0.f, 0.f};
  #pragma unroll 4
  for (int j = 0; j < 512; ++j) {
    float h = fmaxf(r0 * w1[j] + r1 * w1[512 + j] + b1[j], 0.0f);
    #pragma unroll
    for (int q = 0; q < 8; ++q) acc[q] += h * w2[j * 8 + q];
  }
  #pragma unroll
  for (int q = 0; q < 8; ++q) {
    float s = 16.0f / (1.0f + __expf(-acc[q]));
    bias[(q * 64 + lq) * 64 + mk] = s;
  }
}

// ---------------------------------------------------------------------------
__device__ __forceinline__ int win_region(int tok, int wi, int wj) {
  int r = tok >> 3, cc = tok & 7;
  int rh = (wi == 15) ? ((r < 4) ? 1 : 2) : 0;
  int rw = (wj == 15) ? ((cc < 4) ? 1 : 2) : 0;
  return rh * 3 + rw;
}

// ---------------------------------------------------------------------------
// Fused qkv-projection + windowed cosine attention.
// Block = (window, batch), 512 threads = 8 waves, wave = head.
// Phase 1: stage shifted x tile (64x256) fp32->bf16 into LDS (chunk-XOR swizzle).
// Phase 2 (per wave): GEMM C[feat 96][tok 64] = W2(h) @ xs, K=256 (8 ksteps,
//   24 MFMA each). Bias add, l2-norm q/k in C-layout, stage q/k/v to LDS.
// Phase 3: QK^T via mfma(K,Q), +cpb bias, shift mask, softmax (in-lane 16 +
//   shfl 16/32), P^T -> LDS (aliases dead q/k stage). PV: O^T = V^T @ P^T.
// ---------------------------------------------------------------------------
__global__ __launch_bounds__(512, 2) void fused_kernel(
    const float* __restrict__ x, const __bf16* __restrict__ W2,
    const float* __restrict__ bcat, const float* __restrict__ scale,
    const float* __restrict__ cpb, __bf16* __restrict__ out)
{
  __shared__ __align__(16) __bf16 xs[64 * 256];      // 32 KB
  __shared__ __align__(16) __bf16 qkp[8][64 * 72];   // 72 KB q/k stage -> P
  __shared__ __align__(16) __bf16 vst[8][64 * 36];   // 36 KB V [tok][unit]
  const f32x4 zz = {0.f, 0.f, 0.f, 0.f};

  int t = threadIdx.x;
  int h = t >> 6, l = t & 63, g = l >> 4, c = l & 15;
  int win = blockIdx.x, b = blockIdx.y;
  int wi = win >> 4, wj = win & 15;
  bool edge = (wi == 15) || (wj == 15);

  // ---- stage x tile (cyclic shift folded into source address) ----
  {
    int r = t >> 3;                      // local token 0..63
    int q8 = t & 7;                      // 32-float chunk of the 256 channels
    int ht = (wi * 8 + (r >> 3) + 4) & 127;
    int wt = (wj * 8 + (r & 7) + 4) & 127;
    const float* src = x + (size_t)((b * 128 + ht) * 128 + wt) * 256 + q8 * 32;
    #pragma unroll
    for (int q = 0; q < 4; ++q) {
      f32x4 a0 = *(const f32x4*)(src + q * 8);
      f32x4 a1 = *(const f32x4*)(src + q * 8 + 4);
      bf16x8 v;
      #pragma unroll
      for (int j = 0; j < 4; ++j) { v[j] = (__bf16)a0[j]; v[4 + j] = (__bf16)a1[j]; }
      int phys = (q8 * 4 + q) ^ (r & 7);
      *(bf16x8*)&xs[r * 256 + phys * 8] = v;
    }
  }
  __syncthreads();

  int toko[4];
  #pragma unroll
  for (int i = 0; i < 4; ++i) {
    int tok = 16 * i + c;
    int ht = (wi * 8 + (tok >> 3) + 4) & 127;
    int wt = (wj * 8 + (tok & 7) + 4) & 127;
    toko[i] = ((b * 128 + ht) * 128 + wt) * 256;
  }

  // ---- per-head qkv GEMM: acc[ft][tt] = C[ft*16+4g..+3][tt*16+c] ----
  f32x4 acc[6][4];
  #pragma unroll
  for (int ft = 0; ft < 6; ++ft)
    #pragma unroll
    for (int tt = 0; tt < 4; ++tt) acc[ft][tt] = zz;

  const __bf16* Wh = W2 + (size_t)h * 24576;
  #pragma unroll
  for (int ks = 0; ks < 8; ++ks) {
    bf16x8 wf[6], xf[4];
    #pragma unroll
    for (int ft = 0; ft < 6; ++ft)
      wf[ft] = *(const bf16x8*)(Wh + (size_t)((ft * 8 + ks) * 64 + l) * 8);
    #pragma unroll
    for (int tt = 0; tt < 4; ++tt) {
      int phys = (ks * 4 + g) ^ (c & 7);
      xf[tt] = *(const bf16x8*)&xs[(tt * 16 + c) * 256 + phys * 8];
    }
    #pragma unroll
    for (int ft = 0; ft < 6; ++ft)
      #pragma unroll
      for (int tt = 0; tt < 4; ++tt)
        acc[ft][tt] = __builtin_amdgcn_mfma_f32_16x16x32_bf16(wf[ft], xf[tt], acc[ft][tt], 0, 0, 0);
  }

  // ---- bias add (concat layout, col = h*96 + ft*16 + 4g + i) ----
  #pragma unroll
  for (int ft = 0; ft < 6; ++ft) {
    f32x4 bb = *(const f32x4*)&bcat[h * 96 + ft * 16 + 4 * g];
    #pragma unroll
    for (int tt = 0; tt < 4; ++tt) acc[ft][tt] += bb;
  }

  float ls = __expf(fminf(scale[h], 4.6051701859880914f));  // ln(100)

  // ---- l2-normalize q (ft 0,1) and k (ft 2,3); stage q,k,v to LDS ----
  #pragma unroll
  for (int tt = 0; tt < 4; ++tt) {
    float sq = 0.f, sk = 0.f;
    #pragma unroll
    for (int i = 0; i < 4; ++i) {
      sq += acc[0][tt][i] * acc[0][tt][i] + acc[1][tt][i] * acc[1][tt][i];
      sk += acc[2][tt][i] * acc[2][tt][i] + acc[3][tt][i] * acc[3][tt][i];
    }
    sq += __shfl_xor(sq, 16); sq += __shfl_xor(sq, 32);
    sk += __shfl_xor(sk, 16); sk += __shfl_xor(sk, 32);
    float rq = rsqrtf(fmaxf(sq, 1.55e-5f)) * ls;
    float rk = rsqrtf(fmaxf(sk, 1.55e-5f));
    __bf16* row = &qkp[h][(tt * 16 + c) * 72];
    bf16x4 w0, w1, w2, w3, v0, v1;
    #pragma unroll
    for (int i = 0; i < 4; ++i) {
      w0[i] = (__bf16)(acc[0][tt][i] * rq);
      w1[i] = (__bf16)(acc[1][tt][i] * rq);
      w2[i] = (__bf16)(acc[2][tt][i] * rk);
      w3[i] = (__bf16)(acc[3][tt][i] * rk);
      v0[i] = (__bf16)acc[4][tt][i];
      v1[i] = (__bf16)acc[5][tt][i];
    }
    *(bf16x4*)&row[4 * g]      = w0;   // q units 4g..
    *(bf16x4*)&row[16 + 4 * g] = w1;   // q units 16+4g..
    *(bf16x4*)&row[32 + 4 * g] = w2;   // k units 4g..
    *(bf16x4*)&row[48 + 4 * g] = w3;   // k units 16+4g..
    __bf16* vrow = &vst[h][(tt * 16 + c) * 36];
    *(bf16x4*)&vrow[4 * g]      = v0;
    *(bf16x4*)&vrow[16 + 4 * g] = v1;
  }

  // ---- fetch Q/K MFMA fragments (wave-private LDS, compiler orders) ----
  bf16x8 kf[4], qf[4];
  #pragma unroll
  for (int i = 0; i < 4; ++i) {
    kf[i] = *(const bf16x8*)&qkp[h][(16 * i + c) * 72 + 32 + 8 * g];
    qf[i] = *(const bf16x8*)&qkp[h][(16 * i + c) * 72 + 8 * g];
  }

  // ---- QK^T + softmax; P^T overwrites the dead q/k stage ----
  float rsum[4];
  __bf16* Pw = &qkp[h][0];
  #pragma unroll
  for (int nt = 0; nt < 4; ++nt) {
    f32x4 tt4[4];
    #pragma unroll
    for (int mt = 0; mt < 4; ++mt)
      tt4[mt] = __builtin_amdgcn_mfma_f32_16x16x32_bf16(kf[mt], qf[nt], zz, 0, 0, 0);
    int q = nt * 16 + c;
    float p[16];
    #pragma unroll
    for (int mt = 0; mt < 4; ++mt) {
      f32x4 bb = *(const f32x4*)&cpb[(h * 64 + q) * 64 + mt * 16 + 4 * g];
      #pragma unroll
      for (int i = 0; i < 4; ++i) p[mt * 4 + i] = tt4[mt][i] + bb[i];
    }
    if (edge) {
      int regq = win_region(q, wi, wj);
      #pragma unroll
      for (int mt = 0; mt < 4; ++mt)
        #pragma unroll
        for (int i = 0; i < 4; ++i) {
          int k = mt * 16 + 4 * g + i;
          if (win_region(k, wi, wj) != regq) p[mt * 4 + i] -= 100.0f;
        }
    }
    float mx = -1e30f;
    #pragma unroll
    for (int j = 0; j < 16; ++j) mx = fmaxf(mx, p[j]);
    mx = fmaxf(mx, __shfl_xor(mx, 16));
    mx = fmaxf(mx, __shfl_xor(mx, 32));
    float sum = 0.f;
    #pragma unroll
    for (int j = 0; j < 16; ++j) { p[j] = __expf(p[j] - mx); sum += p[j]; }
    sum += __shfl_xor(sum, 16); sum += __shfl_xor(sum, 32);
    rsum[nt] = sum;
    #pragma unroll
    for (int mt = 0; mt < 4; ++mt) {
      bf16x4 px = { (__bf16)p[mt * 4 + 0], (__bf16)p[mt * 4 + 1],
                    (__bf16)p[mt * 4 + 2], (__bf16)p[mt * 4 + 3] };
      *(bf16x4*)&Pw[q * 72 + mt * 16 + 4 * g] = px;
    }
  }

  // ---- O^T = V^T @ P^T ----
  #pragma unroll
  for (int mh = 0; mh < 2; ++mh) {
    f32x4 oacc[4];
    #pragma unroll
    for (int nt = 0; nt < 4; ++nt) oacc[nt] = zz;
    #pragma unroll
    for (int ks = 0; ks < 2; ++ks) {
      bf16x8 va;
      #pragma unroll
      for (int j = 0; j < 8; ++j)
        va[j] = vst[h][(32 * ks + 8 * g + j) * 36 + 16 * mh + c];
      #pragma unroll
      for (int nt = 0; nt < 4; ++nt) {
        bf16x8 pfr = *(const bf16x8*)&Pw[(nt * 16 + c) * 72 + 32 * ks + 8 * g];
        oacc[nt] = __builtin_amdgcn_mfma_f32_16x16x32_bf16(va, pfr, oacc[nt], 0, 0, 0);
      }
    }
    #pragma unroll
    for (int nt = 0; nt < 4; ++nt) {
      float rinv = 1.0f / rsum[nt];
      bf16x4 ov = { (__bf16)(oacc[nt][0] * rinv), (__bf16)(oacc[nt][1] * rinv),
                    (__bf16)(oacc[nt][2] * rinv), (__bf16)(oacc[nt][3] * rinv) };
      *(bf16x4*)(out + toko[nt] + h * 32 + 16 * mh + 4 * g) = ov;
    }
  }
}

// ---------------------------------------------------------------------------
// proj GEMM: C[M,256] = A[M,256] @ pT[256,256]^T, fp32 out + proj_b.
// (unchanged known-correct structure; target of next round)
// ---------------------------------------------------------------------------
__global__ __launch_bounds__(256) void proj_kernel(
    const __bf16* __restrict__ A, const __bf16* __restrict__ BT,
    float* __restrict__ Cout, const float* __restrict__ pb)
{
  const int K = 256, N = 256, NB = 2;
  __shared__ __align__(16) __bf16 lA[128 * 64];
  __shared__ __align__(16) __bf16 lB[128 * 64];
  int t = threadIdx.x;
  int wv = t >> 6, l = t & 63;
  int g = l >> 4, c = l & 15;
  int wr = wv >> 1, wc = wv & 1;

  int cpx = gridDim.x >> 3;
  int lin = (blockIdx.x & 7) * cpx + (blockIdx.x >> 3);
  int mblk = lin / NB;
  int nblk = lin - mblk * NB;

  int srow = wv * 8 + (l >> 3);
  const __bf16* Ab = A + (size_t)mblk * 128 * K;
  const __bf16* Bb = BT + (size_t)nblk * 128 * K;

  f32x4 acc[4][4];
  #pragma unroll
  for (int i = 0; i < 4; ++i)
    #pragma unroll
    for (int j = 0; j < 4; ++j) acc[i][j] = (f32x4){0.f, 0.f, 0.f, 0.f};

  for (int kt = 0; kt < 4; ++kt) {
    bf16x8 ra[4], rb[4];
    #pragma unroll
    for (int p = 0; p < 4; ++p) {
      ra[p] = *(const bf16x8*)(Ab + (size_t)(p * 32 + srow) * K + kt * 64 + (l & 7) * 8);
      rb[p] = *(const bf16x8*)(Bb + (size_t)(p * 32 + srow) * K + kt * 64 + (l & 7) * 8);
    }
    __syncthreads();
    #pragma unroll
    for (int p = 0; p < 4; ++p) {
      int row = p * 32 + srow;
      int phys = (l & 7) ^ (row & 7);
      *(bf16x8*)&lA[row * 64 + phys * 8] = ra[p];
      *(bf16x8*)&lB[row * 64 + phys * 8] = rb[p];
    }
    __syncthreads();
    #pragma unroll
    for (int kk = 0; kk < 2; ++kk) {
      bf16x8 af[4], bfr[4];
      #pragma unroll
      for (int mt = 0; mt < 4; ++mt) {
        int row = wr * 64 + mt * 16 + c;
        int ch = ((kk << 2) | g) ^ (c & 7);
        af[mt] = *(const bf16x8*)&lA[row * 64 + ch * 8];
      }
      #pragma unroll
      for (int nt = 0; nt < 4; ++nt) {
        int row = wc * 64 + nt * 16 + c;
        int ch = ((kk << 2) | g) ^ (c & 7);
        bfr[nt] = *(const bf16x8*)&lB[row * 64 + ch * 8];
      }
      #pragma unroll
      for (int mt = 0; mt < 4; ++mt)
        #pragma unroll
        for (int nt = 0; nt < 4; ++nt)
          acc[mt][nt] = __builtin_amdgcn_mfma_f32_16x16x32_bf16(af[mt], bfr[nt], acc[mt][nt], 0, 0, 0);
    }
  }

  #pragma unroll
  for (int mt = 0; mt < 4; ++mt) {
    #pragma unroll
    for (int nt = 0; nt < 4; ++nt) {
      int row0 = mblk * 128 + wr * 64 + mt * 16 + 4 * g;
      int col  = nblk * 128 + wc * 64 + nt * 16 + c;
      float bias = pb[col];
      #pragma unroll
      for (int i = 0; i < 4; ++i)
        Cout[(size_t)(row0 + i) * N + col] = acc[mt][nt][i] + bias;
    }
  }
}

// ---------------------------------------------------------------------------
extern "C" void kernel_launch(void* const* d_in, const int* in_sizes, int n_in,
                              void* d_out, int out_size, void* d_ws, size_t ws_size,
                              hipStream_t stream)
{
  const float* x      = (const float*)d_in[0];
  const float* qkv_w  = (const float*)d_in[1];
  const float* q_bias = (const float*)d_in[2];
  const float* v_bias = (const float*)d_in[3];
  const float* scale  = (const float*)d_in[4];
  const float* cpb_w1 = (const float*)d_in[5];
  const float* cpb_b1 = (const float*)d_in[6];
  const float* cpb_w2 = (const float*)d_in[7];
  const float* proj_w = (const float*)d_in[8];
  const float* proj_b = (const float*)d_in[9];

  char* ws = (char*)d_ws;
  // layout (bytes):
  //   [0, 134217728)           attn-out bf16 [262144][256]
  //   [134217728, 134610944)   W2 bf16 packed qkv weights
  //   [134610944, 134742016)   proj_w^T bf16 [256][256]
  //   [134742016, 134745088)   bcat f32[768]
  //   [134745088, 134876160)   cpb bias f32 [8][64][64]
  __bf16* aout = (__bf16*)(ws);
  __bf16* W2   = (__bf16*)(ws + 134217728LL);
  __bf16* pT   = (__bf16*)(ws + 134610944LL);
  float*  bcat = (float*) (ws + 134742016LL);
  float*  cpb  = (float*) (ws + 134745088LL);

  wprep_kernel<<<355, 256, 0, stream>>>(qkv_w, proj_w, q_bias, v_bias, W2, pT, bcat);
  cpb_kernel<<<16, 256, 0, stream>>>(cpb_w1, cpb_b1, cpb_w2, cpb);
  fused_kernel<<<dim3(256, 16), 512, 0, stream>>>(x, W2, bcat, scale, cpb, aout);
  proj_kernel<<<4096, 256, 0, stream>>>(aout, pT, (float*)d_out, proj_b);
}